// Round 2
// baseline (1015.078 us; speedup 1.0000x reference)
//
#include <hip/hip_runtime.h>
#include <cstdint>

#define BM 128
#define BN 128
#define BK 32

typedef __attribute__((ext_vector_type(8))) short short8;
typedef _Float16 half8 __attribute__((ext_vector_type(8)));
typedef __attribute__((ext_vector_type(4))) float floatx4;

union H8 { short8 s; half8 h; };

static constexpr float SIBS   = 0.044194173824159216f; // 1/sqrt(512)
static constexpr float LS_INV = 1.0f / 2048.0f;

__device__ __forceinline__ unsigned short f2bf(float x){
    union { float f; unsigned u32; } v; v.f = x;
    unsigned r = ((v.u32 >> 16) & 1u) + 0x7fffu;
    return (unsigned short)((v.u32 + r) >> 16);
}
__device__ __forceinline__ void split_f16(float x, unsigned short& h, unsigned short& s){
    _Float16 hh = (_Float16)x;
    _Float16 ss = (_Float16)((x - (float)hh) * 2048.0f);
    union { _Float16 f; unsigned short u; } a, b;
    a.f = hh; b.f = ss;
    h = a.u; s = b.u;
}

#define GLDS(g, l) __builtin_amdgcn_global_load_lds( \
    (const __attribute__((address_space(1))) void*)(g), \
    (__attribute__((address_space(3))) void*)(l), 16, 0, 0)

// ---- prep: fp32 src[R][C] -> transposed fp16 hi/lo-scaled pair [C][R] ----
__global__ void prep_split16_T(const float* __restrict__ src,
                               unsigned short* __restrict__ hiT,
                               unsigned short* __restrict__ lsT,
                               int R, int C)
{
    __shared__ float t[32][33];
    int c0 = blockIdx.x * 32, r0 = blockIdx.y * 32;
    int tx = threadIdx.x & 31, ty = threadIdx.x >> 5;
#pragma unroll
    for (int k = 0; k < 4; k++){
        int r = ty + k*8;
        t[r][tx] = src[(size_t)(r0 + r) * C + c0 + tx];
    }
    __syncthreads();
#pragma unroll
    for (int k = 0; k < 4; k++){
        int r = ty + k*8;
        float x = t[tx][r]; // = src[r0+tx][c0+r]
        unsigned short h, s;
        split_f16(x, h, s);
        size_t o = (size_t)(c0 + r) * R + r0 + tx;
        hiT[o] = h; lsT[o] = s;
    }
}

// ---- prep: Wc2 = WcL + WcR (512x512), transposed fp16 hi/lo pair ----
__global__ void prep_wc2_T(const float* __restrict__ Wc,
                           unsigned short* __restrict__ hiT,
                           unsigned short* __restrict__ lsT)
{
    __shared__ float t[32][33];
    int c0 = blockIdx.x * 32, r0 = blockIdx.y * 32;
    int tx = threadIdx.x & 31, ty = threadIdx.x >> 5;
#pragma unroll
    for (int k = 0; k < 4; k++){
        int r = ty + k*8;
        t[r][tx] = Wc[(size_t)(r0 + r) * 1024 + c0 + tx]
                 + Wc[(size_t)(r0 + r) * 1024 + 512 + c0 + tx];
    }
    __syncthreads();
#pragma unroll
    for (int k = 0; k < 4; k++){
        int r = ty + k*8;
        float x = t[tx][r];
        unsigned short h, s;
        split_f16(x, h, s);
        size_t o = (size_t)(c0 + r) * 512 + r0 + tx;
        hiT[o] = h; lsT[o] = s;
    }
}

// ---- prep: fp32 src[R][C] -> transposed bf16 [C][R] ----
__global__ void prep_bf16_T(const float* __restrict__ src,
                            unsigned short* __restrict__ dstT,
                            int R, int C)
{
    __shared__ float t[32][33];
    int c0 = blockIdx.x * 32, r0 = blockIdx.y * 32;
    int tx = threadIdx.x & 31, ty = threadIdx.x >> 5;
#pragma unroll
    for (int k = 0; k < 4; k++){
        int r = ty + k*8;
        t[r][tx] = src[(size_t)(r0 + r) * C + c0 + tx];
    }
    __syncthreads();
#pragma unroll
    for (int k = 0; k < 4; k++){
        int r = ty + k*8;
        dstT[(size_t)(c0 + r) * R + r0 + tx] = f2bf(t[tx][r]);
    }
}

// ---------------- unified GEMM (2-phase double-buffered pipeline) ----------------
// MODE 0: h0   — A = gathered emb rows (fp32 -> fp16 2-limb in-kernel, T14 split),
//                writes nodes0 fp32 + hi/lo limb arrays
// MODE 1: tree — A = pre-split limb arrays via GLDS, +bc+sib,
//                writes nodes_next fp32 (+ limbs when DEPTH==0). NO atomics.
// MODE 2: out  — A = pooled (bf16), B = WoutT (bf16), fp32 logits (+bout)
// MODE 3: agg  — A = S limbs, B = Wc2T limbs; epilogue fuses
//                pooled = bf16((h0 + S@Wc2 + m*constv) / cnt)
// B pre-transposed [N][K], K=512. MODE!=2: BTh/BTl fp16 pair; MODE 2: BTh bf16.
//
// Pipeline per K-iter: STAGE(next tile -> other buffer) ; compute(current) ;
// __syncthreads() (full vmcnt+lgkm drain => race-free; load latency hides
// under the MFMA phase instead of an immediate drain).
template<int MODE, int DEPTH>
__global__ __launch_bounds__(256, 2)
void gemm_k(const unsigned short* __restrict__ Abf,
            const unsigned short* __restrict__ Agh,
            const unsigned short* __restrict__ Agl,
            const unsigned short* __restrict__ BTh,
            const unsigned short* __restrict__ BTl,
            const float* __restrict__ bias,
            const int* __restrict__ tokens,
            const float* __restrict__ emb,
            const float* __restrict__ sib,
            const float* __restrict__ mArr,
            const float* __restrict__ cinv,
            const float* __restrict__ h0,
            float* __restrict__ nodes_next,
            unsigned short* __restrict__ nxh,
            unsigned short* __restrict__ nxl,
            float* __restrict__ f32out,
            unsigned short* __restrict__ pooled,
            float* __restrict__ out,
            int N)
{
    constexpr int K = 512;
    constexpr int TS = BM * BK;           // 4096 shorts = 8 KB per tile buffer
    // fragment-contiguous LDS: slot s = kq*128 + m, 8 elems (16B) per slot
    __shared__ __align__(16) unsigned short Ah[2*TS];
    __shared__ __align__(16) unsigned short Bh[2*TS];
    __shared__ __align__(16) unsigned short Al[(MODE==2) ? 8 : 2*TS];
    __shared__ __align__(16) unsigned short Bl[(MODE==2) ? 8 : 2*TS];

    const int tid = threadIdx.x;
    const int w = tid >> 6, l = tid & 63;
    const int wr = w >> 1, wc = w & 1;
    const int row0 = blockIdx.x * BM;
    const int n0   = blockIdx.y * BN;
    const int q = l >> 4, lm = l & 15;

    floatx4 acc[4][4]  = {};
    floatx4 accx[4][4] = {};

    // A-source row pointer (MODE 0: emb gather, split in VGPRs)
    const float* aptr = nullptr;
    const int am = tid & 127, kq0 = tid >> 7;
    if (MODE == 0) aptr = emb + (long)tokens[row0 + am] * K;

    long arow0 = 0, arow1 = 0;
    if (MODE != 0){
        arow0 = (long)(row0 + l) * K;
        arow1 = (long)(row0 + 64 + l) * K;
    }
    const long brow0 = (long)(n0 + l) * K;
    const long brow1 = (long)(n0 + 64 + l) * K;

// stage one K-tile (kk) into LDS buffer (buf) — GLDS paths only
#define STAGE_TILE(buf, kk)                                                  \
    {                                                                        \
        char* bhp = (char*)Bh + (buf)*8192 + w*2048;                         \
        GLDS(BTh + brow0 + (kk) + w*8, bhp);                                 \
        GLDS(BTh + brow1 + (kk) + w*8, bhp + 1024);                         \
        if (MODE != 2){                                                      \
            char* blp = (char*)Bl + (buf)*8192 + w*2048;                     \
            GLDS(BTl + brow0 + (kk) + w*8, blp);                             \
            GLDS(BTl + brow1 + (kk) + w*8, blp + 1024);                     \
        }                                                                    \
        if (MODE == 1 || MODE == 3){                                         \
            char* ahp = (char*)Ah + (buf)*8192 + w*2048;                     \
            char* alp = (char*)Al + (buf)*8192 + w*2048;                     \
            GLDS(Agh + arow0 + (kk) + w*8, ahp);                             \
            GLDS(Agh + arow1 + (kk) + w*8, ahp + 1024);                     \
            GLDS(Agl + arow0 + (kk) + w*8, alp);                             \
            GLDS(Agl + arow1 + (kk) + w*8, alp + 1024);                     \
        } else if (MODE == 2){                                               \
            char* ahp = (char*)Ah + (buf)*8192 + w*2048;                     \
            GLDS(Abf + arow0 + (kk) + w*8, ahp);                             \
            GLDS(Abf + arow1 + (kk) + w*8, ahp + 1024);                     \
        }                                                                    \
    }

    // ---- prologue: stage tile 0 into buffer 0 ----
    STAGE_TILE(0, 0);
    if (MODE == 0){
#pragma unroll
        for (int tt = 0; tt < 2; tt++){
            int kq = kq0 + 2*tt;
            const float* src = aptr + kq*8;
            float xs[8];
            *(floatx4*)&xs[0] = *(const floatx4*)(src);
            *(floatx4*)&xs[4] = *(const floatx4*)(src + 4);
            unsigned short h8[8], l8[8];
#pragma unroll
            for (int e = 0; e < 8; e++) split_f16(xs[e], h8[e], l8[e]);
            int s = kq*128 + am;
            *(short8*)&Ah[s*8] = *(const short8*)h8;
            *(short8*)&Al[s*8] = *(const short8*)l8;
        }
    }
    __syncthreads();

    constexpr int nIter = K / BK; // 16
    for (int t = 0; t < nIter; t++){
        const int cur = t & 1, nxt = cur ^ 1;
        const bool more = (t + 1 < nIter);
        const int knext = (t + 1) * BK;

        if (more) STAGE_TILE(nxt, knext);

        // MODE 0: issue next-tile A loads early (T14) — consumed after MFMAs
        floatx4 pA0, pA1, pA2, pA3;
        if (MODE == 0 && more){
            const float* s0 = aptr + knext + kq0*8;
            const float* s1 = aptr + knext + (kq0+2)*8;
            pA0 = *(const floatx4*)(s0); pA1 = *(const floatx4*)(s0 + 4);
            pA2 = *(const floatx4*)(s1); pA3 = *(const floatx4*)(s1 + 4);
        }

        const int off = cur * TS;
        H8 bh[4], bl[4];
#pragma unroll
        for (int j = 0; j < 4; j++){
            bh[j].s = *(const short8*)&Bh[off + (q*128 + wc*64 + j*16 + lm)*8];
            if (MODE != 2)
                bl[j].s = *(const short8*)&Bl[off + (q*128 + wc*64 + j*16 + lm)*8];
        }
#pragma unroll
        for (int i = 0; i < 4; i++){
            H8 ah; ah.s = *(const short8*)&Ah[off + (q*128 + wr*64 + i*16 + lm)*8];
            if (MODE != 2){
                H8 al; al.s = *(const short8*)&Al[off + (q*128 + wr*64 + i*16 + lm)*8];
#pragma unroll
                for (int j = 0; j < 4; j++)
                    acc[i][j]  = __builtin_amdgcn_mfma_f32_16x16x32_f16(ah.h, bh[j].h, acc[i][j], 0, 0, 0);
#pragma unroll
                for (int j = 0; j < 4; j++)
                    accx[i][j] = __builtin_amdgcn_mfma_f32_16x16x32_f16(ah.h, bl[j].h, accx[i][j], 0, 0, 0);
#pragma unroll
                for (int j = 0; j < 4; j++)
                    accx[i][j] = __builtin_amdgcn_mfma_f32_16x16x32_f16(al.h, bh[j].h, accx[i][j], 0, 0, 0);
            } else {
#pragma unroll
                for (int j = 0; j < 4; j++)
                    acc[i][j] = __builtin_amdgcn_mfma_f32_16x16x32_bf16(ah.s, bh[j].s, acc[i][j], 0, 0, 0);
            }
        }

        // MODE 0: convert + write next A tile into the other buffer
        if (MODE == 0 && more){
            float xs[8];
            unsigned short h8[8], l8[8];
            *(floatx4*)&xs[0] = pA0; *(floatx4*)&xs[4] = pA1;
#pragma unroll
            for (int e = 0; e < 8; e++) split_f16(xs[e], h8[e], l8[e]);
            int s = kq0*128 + am;
            *(short8*)&Ah[nxt*TS + s*8] = *(const short8*)h8;
            *(short8*)&Al[nxt*TS + s*8] = *(const short8*)l8;
            *(floatx4*)&xs[0] = pA2; *(floatx4*)&xs[4] = pA3;
#pragma unroll
            for (int e = 0; e < 8; e++) split_f16(xs[e], h8[e], l8[e]);
            s = (kq0+2)*128 + am;
            *(short8*)&Ah[nxt*TS + s*8] = *(const short8*)h8;
            *(short8*)&Al[nxt*TS + s*8] = *(const short8*)l8;
        }
        __syncthreads();
    }
#undef STAGE_TILE

    // epilogue: D[row=(l>>4)*4+r][col=l&15] per 16x16 frag
#pragma unroll
    for (int i = 0; i < 4; i++){
        int rbase = row0 + wr*64 + i*16 + q*4;
#pragma unroll
        for (int j = 0; j < 4; j++){
            int col = n0 + wc*64 + j*16 + lm;
            float badd = 0.f, bsum = 0.f;
            int half = 0, h = 0;
            if (MODE == 0 || MODE == 2) badd = bias[col];
            if (MODE == 1){
                half = col >> 9; h = col & 511;
                badd = bias[col] + SIBS * sib[half*512 + h];
            }
            if (MODE == 3)
                bsum = bias[col] + bias[512 + col] + SIBS * (sib[col] + sib[512 + col]);
#pragma unroll
            for (int r = 0; r < 4; r++){
                int row = rbase + r;
                float v = acc[i][j][r];
                if (MODE != 2) v += accx[i][j][r] * LS_INV;
                if (MODE == 0){
                    v += badd;
                    long o = (long)row*512 + col;
                    f32out[o] = v;
                    unsigned short hh, ss; split_f16(v, hh, ss);
                    nxh[o] = hh; nxl[o] = ss;
                } else if (MODE == 1){
                    v += badd;
                    long o = (long)(2*row + half)*512 + h;
                    nodes_next[o] = v;
                    if (DEPTH == 0){
                        unsigned short hh, ss; split_f16(v, hh, ss);
                        nxh[o] = hh; nxl[o] = ss;
                    }
                } else if (MODE == 3){
                    long o = (long)row*512 + col;
                    float outv = (h0[o] + v + mArr[row]*bsum) * cinv[row];
                    pooled[o] = f2bf(outv);
                } else {
                    out[(long)row*(long)N + col] = v + badd;
                }
            }
        }
    }
}

// ---- gate: x = (node + 0.01*dep_d) . Wg + bg ; expand = (x>0) & active ----
__global__ void gate_k(const float* __restrict__ nodes,
                       const float* __restrict__ Wg,
                       const float* __restrict__ bg,
                       const float* __restrict__ deprow,
                       const unsigned char* __restrict__ eprev,
                       unsigned char* __restrict__ e,
                       int depth)
{
    int row = blockIdx.x * 4 + (threadIdx.x >> 6);
    int l = threadIdx.x & 63;
    const float* nr = nodes + (long)row * 512;
    float s = 0.f;
#pragma unroll
    for (int t = 0; t < 8; t++){
        int h = t*64 + l;
        s += (nr[h] + 0.01f * deprow[h]) * Wg[h];
    }
#pragma unroll
    for (int off = 32; off > 0; off >>= 1) s += __shfl_down(s, off);
    if (l == 0){
        float x = s + bg[0];
        unsigned char a = (depth == 0) ? (unsigned char)1 : eprev[row >> 1];
        e[row] = (unsigned char)((x > 0.f) && a);
    }
}

// ---- masked sum: S[n] = sum over expanded nodes at all depths; m, 1/cnt ----
__global__ void msum_k(const float* __restrict__ nodes0,
                       const float* __restrict__ nodes1,
                       const float* __restrict__ nodes2,
                       const unsigned char* __restrict__ e0,
                       const unsigned char* __restrict__ e1,
                       const unsigned char* __restrict__ e2,
                       unsigned short* __restrict__ Sh,
                       unsigned short* __restrict__ Sl,
                       float* __restrict__ mArr,
                       float* __restrict__ cinv)
{
    int n = blockIdx.x;
    float a0  = (float)e0[n];
    float a10 = (float)e1[2*n],   a11 = (float)e1[2*n+1];
    float a20 = (float)e2[4*n],   a21 = (float)e2[4*n+1];
    float a22 = (float)e2[4*n+2], a23 = (float)e2[4*n+3];
    if (threadIdx.x == 0){
        float m = a0 + a10 + a11 + a20 + a21 + a22 + a23;
        mArr[n] = m;
        cinv[n] = 1.f / (1.f + 2.f * m);
    }
    const float* p0 = nodes0 + (long)n * 512;
    const float* p1 = nodes1 + (long)(2*n) * 512;
    const float* p2 = nodes2 + (long)(4*n) * 512;
    for (int c = threadIdx.x; c < 512; c += 256){
        float s = a0 * p0[c]
                + a10 * p1[c]        + a11 * p1[512 + c]
                + a20 * p2[c]        + a21 * p2[512 + c]
                + a22 * p2[1024 + c] + a23 * p2[1536 + c];
        unsigned short hh, ss; split_f16(s, hh, ss);
        long o = (long)n * 512 + c;
        Sh[o] = hh; Sl[o] = ss;
    }
}

extern "C" void kernel_launch(void* const* d_in, const int* in_sizes, int n_in,
                              void* d_out, int out_size, void* d_ws, size_t ws_size,
                              hipStream_t stream)
{
    const int*   tokens = (const int*)d_in[0];
    const float* emb    = (const float*)d_in[1];
    const float* Wp     = (const float*)d_in[2];
    const float* bp     = (const float*)d_in[3];
    const float* Wc     = (const float*)d_in[4];
    const float* bc     = (const float*)d_in[5];
    const float* Wg     = (const float*)d_in[6];
    const float* bg     = (const float*)d_in[7];
    const float* dep    = (const float*)d_in[8];
    const float* sib    = (const float*)d_in[9];
    const float* Wout   = (const float*)d_in[10];
    const float* bout   = (const float*)d_in[11];

    if (ws_size < ((size_t)48 << 20)) return; // need ~42 MB scratch

    char* w = (char*)d_ws;
    auto alloc = [&](size_t bytes)->char*{
        char* p = w; w += (bytes + 255) & ~(size_t)255; return p;
    };
    unsigned short* WpT_h  = (unsigned short*)alloc((size_t)512*512*2);
    unsigned short* WpT_l  = (unsigned short*)alloc((size_t)512*512*2);
    unsigned short* WcT_h  = (unsigned short*)alloc((size_t)1024*512*2);
    unsigned short* WcT_l  = (unsigned short*)alloc((size_t)1024*512*2);
    unsigned short* Wc2T_h = (unsigned short*)alloc((size_t)512*512*2);
    unsigned short* Wc2T_l = (unsigned short*)alloc((size_t)512*512*2);
    unsigned short* WoutT  = (unsigned short*)alloc((size_t)32000*512*2);
    unsigned short* pooled = (unsigned short*)alloc((size_t)4096*512*2);
    unsigned char*  e0     = (unsigned char*)alloc(4096);
    unsigned char*  e1     = (unsigned char*)alloc(8192);
    unsigned char*  e2     = (unsigned char*)alloc(16384);

    // All node/limb intermediates live inside d_out (500 MiB) — each is fully
    // consumed before the final GEMM overwrites the buffer with logits.
    char* ob = (char*)d_out;
    float*          nodes0 = (float*)(ob + ((size_t) 64 << 20)); //  8.4 MB
    unsigned short* n0h    = (unsigned short*)(ob + ((size_t) 80 << 20)); // 4.2
    unsigned short* n0l    = (unsigned short*)(ob + ((size_t) 88 << 20)); // 4.2
    float*          nodes1 = (float*)(ob + ((size_t) 96 << 20)); // 16.8 MB
    unsigned short* n1h    = (unsigned short*)(ob + ((size_t)128 << 20)); // 8.4
    unsigned short* n1l    = (unsigned short*)(ob + ((size_t)144 << 20)); // 8.4
    float*          nodes2 = (float*)(ob + ((size_t)160 << 20)); // 33.6 MB
    unsigned short* Sh     = (unsigned short*)(ob + ((size_t)200 << 20)); // 4.2
    unsigned short* Sl     = (unsigned short*)(ob + ((size_t)208 << 20)); // 4.2
    float*          mArr   = (float*)(ob + ((size_t)216 << 20)); // 16 KB
    float*          cinvA  = (float*)(ob + ((size_t)217 << 20)); // 16 KB
    float*          out    = (float*)d_out;

    prep_split16_T<<<dim3(16, 16),   256, 0, stream>>>(Wp, WpT_h, WpT_l, 512, 512);
    prep_split16_T<<<dim3(32, 16),   256, 0, stream>>>(Wc, WcT_h, WcT_l, 512, 1024);
    prep_wc2_T    <<<dim3(16, 16),   256, 0, stream>>>(Wc, Wc2T_h, Wc2T_l);
    prep_bf16_T   <<<dim3(1000, 16), 256, 0, stream>>>(Wout, WoutT, 512, 32000);

    // h0 = emb[tok] @ Wp + bp  -> nodes0 fp32 + limb pair
    gemm_k<0,0><<<dim3(32, 4), 256, 0, stream>>>(nullptr, nullptr, nullptr,
        WpT_h, WpT_l, bp, tokens, emb, nullptr, nullptr, nullptr, nullptr,
        nullptr, n0h, n0l, nodes0, nullptr, nullptr, 512);

    gate_k<<<1024, 256, 0, stream>>>(nodes0, Wg, bg, dep + 0, nullptr, e0, 0);

    // depth-0 children -> nodes1 fp32 + limbs (no atomics)
    gemm_k<1,0><<<dim3(32, 8), 256, 0, stream>>>(nullptr, n0h, n0l,
        WcT_h, WcT_l, bc, nullptr, nullptr, sib, nullptr, nullptr, nullptr,
        nodes1, n1h, n1l, nullptr, nullptr, nullptr, 1024);

    gate_k<<<2048, 256, 0, stream>>>(nodes1, Wg, bg, dep + 512, e0, e1, 1);

    // depth-1 children -> nodes2 fp32 only (depth-2 child GEMM eliminated)
    gemm_k<1,1><<<dim3(64, 8), 256, 0, stream>>>(nullptr, n1h, n1l,
        WcT_h, WcT_l, bc, nullptr, nullptr, sib, nullptr, nullptr, nullptr,
        nodes2, nullptr, nullptr, nullptr, nullptr, nullptr, 1024);

    gate_k<<<4096, 256, 0, stream>>>(nodes2, Wg, bg, dep + 1024, e1, e2, 2);

    // S = masked sum of expanded nodes across depths; m, 1/cnt per token
    msum_k<<<4096, 256, 0, stream>>>(nodes0, nodes1, nodes2, e0, e1, e2,
        Sh, Sl, mArr, cinvA);

    // pooled = bf16((h0 + S@Wc2 + m*const) / cnt)
    gemm_k<3,0><<<dim3(32, 4), 256, 0, stream>>>(nullptr, Sh, Sl,
        Wc2T_h, Wc2T_l, bc, nullptr, nullptr, sib, mArr, cinvA, nodes0,
        nullptr, nullptr, nullptr, nullptr, pooled, nullptr, 512);

    // logits = pooled @ Wout + bout (bf16 MFMA, fp32 out)
    gemm_k<2,0><<<dim3(32, 250), 256, 0, stream>>>(pooled, nullptr, nullptr,
        WoutT, nullptr, bout, nullptr, nullptr, nullptr, nullptr, nullptr, nullptr,
        nullptr, nullptr, nullptr, nullptr, nullptr, out, 32000);
}

// Round 3
// 1003.299 us; speedup vs baseline: 1.0117x; 1.0117x over previous
//
#include <hip/hip_runtime.h>
#include <cstdint>

#define BM 128
#define BN 128
#define BK 32

typedef __attribute__((ext_vector_type(8))) short short8;
typedef _Float16 half8 __attribute__((ext_vector_type(8)));
typedef __attribute__((ext_vector_type(4))) float floatx4;

union H8 { short8 s; half8 h; };

static constexpr float SIBS   = 0.044194173824159216f; // 1/sqrt(512)
static constexpr float LS_INV = 1.0f / 2048.0f;

__device__ __forceinline__ unsigned short f2bf(float x){
    union { float f; unsigned u32; } v; v.f = x;
    unsigned r = ((v.u32 >> 16) & 1u) + 0x7fffu;
    return (unsigned short)((v.u32 + r) >> 16);
}
__device__ __forceinline__ void split_f16(float x, unsigned short& h, unsigned short& s){
    _Float16 hh = (_Float16)x;
    _Float16 ss = (_Float16)((x - (float)hh) * 2048.0f);
    union { _Float16 f; unsigned short u; } a, b;
    a.f = hh; b.f = ss;
    h = a.u; s = b.u;
}

#define GLDS(g, l) __builtin_amdgcn_global_load_lds( \
    (const __attribute__((address_space(1))) void*)(g), \
    (__attribute__((address_space(3))) void*)(l), 16, 0, 0)

// ---------------- fused prep (one dispatch) ----------------
// blocks [0,256)        : WpT hi/lo split-transpose (512x512)
// blocks [256,768)      : WcT hi/lo split-transpose (512x1024)
// blocks [768,1024)     : Wc2T = (WcL+WcR) hi/lo split-transpose (512x512)
// blocks [1024,17024)   : WoutT bf16 transpose (512x32000)
// blocks [17024,17032)  : zero gacc (28672 floats)
// block  17032          : cgate[d] = 0.01*dep[d].Wg + bg, d=0..2
__global__ void prep_all(const float* __restrict__ Wp, const float* __restrict__ Wc,
                         const float* __restrict__ Wout, const float* __restrict__ Wg,
                         const float* __restrict__ bg, const float* __restrict__ dep,
                         unsigned short* __restrict__ WpT_h, unsigned short* __restrict__ WpT_l,
                         unsigned short* __restrict__ WcT_h, unsigned short* __restrict__ WcT_l,
                         unsigned short* __restrict__ Wc2T_h, unsigned short* __restrict__ Wc2T_l,
                         unsigned short* __restrict__ WoutT,
                         float* __restrict__ gacc, float* __restrict__ cgate)
{
    int bid = blockIdx.x;
    if (bid >= 17024){
        if (bid < 17032){
            int base = (bid - 17024)*3584 + threadIdx.x;
#pragma unroll
            for (int k = 0; k < 14; k++) gacc[base + k*256] = 0.f;
        } else {
            int wv = threadIdx.x >> 6, l = threadIdx.x & 63;
            if (wv < 3){
                float s = 0.f;
#pragma unroll
                for (int t = 0; t < 8; t++){
                    int h = t*64 + l;
                    s += dep[wv*512 + h] * Wg[h];
                }
#pragma unroll
                for (int off = 32; off > 0; off >>= 1) s += __shfl_down(s, off);
                if (l == 0) cgate[wv] = 0.01f*s + bg[0];
            }
        }
        return;
    }
    __shared__ float t[32][33];
    const float* src = nullptr;
    unsigned short *dh = nullptr, *dl = nullptr;
    int C = 512, bx, by; bool sum2 = false;
    if (bid < 256){ src=Wp; dh=WpT_h; dl=WpT_l; C=512; bx=bid&15; by=bid>>4; }
    else if (bid < 768){ int rel=bid-256; src=Wc; dh=WcT_h; dl=WcT_l; C=1024; bx=rel&31; by=rel>>5; }
    else if (bid < 1024){ int rel=bid-768; src=Wc; dh=Wc2T_h; dl=Wc2T_l; C=512; sum2=true; bx=rel&15; by=rel>>4; }
    else { int rel=bid-1024; src=Wout; dh=WoutT; dl=nullptr; C=32000; bx=rel%1000; by=rel/1000; }
    int c0 = bx*32, r0 = by*32;
    int tx = threadIdx.x & 31, ty = threadIdx.x >> 5;
#pragma unroll
    for (int k = 0; k < 4; k++){
        int r = ty + k*8;
        float x;
        if (sum2) x = Wc[(size_t)(r0+r)*1024 + c0+tx] + Wc[(size_t)(r0+r)*1024 + 512 + c0+tx];
        else      x = src[(size_t)(r0+r)*C + c0+tx];
        t[r][tx] = x;
    }
    __syncthreads();
#pragma unroll
    for (int k = 0; k < 4; k++){
        int r = ty + k*8;
        float x = t[tx][r]; // = src[r0+tx][c0+r]
        size_t o = (size_t)(c0+r)*512 + r0+tx;
        if (dl){
            unsigned short h, s; split_f16(x, h, s);
            dh[o] = h; dl[o] = s;
        } else {
            dh[o] = f2bf(x);
        }
    }
}

// ---------------- unified GEMM ----------------
// MODE 0: h0   — A = gathered emb rows (fp32 -> fp16 2-limb in-kernel),
//                writes nodes0 fp32 + limb arrays; gate-dot atomics -> gacc
// MODE 1: tree — A = pre-split limb arrays via GLDS, +bc+sib,
//                writes nodes_next fp32 (+ limbs when DEPTH==0); gate-dot -> gacc
// MODE 2: out  — A = pooled (bf16), B = WoutT (bf16), fp32 logits (+bout),
//                1D grid with XCD-bijective swizzle
// MODE 3: agg  — A = S limbs, B = Wc2T limbs; epilogue fuses
//                pooled = bf16((h0 + S@Wc2 + m*constv) / cnt)
// B pre-transposed [N][K], K=512. MODE!=2: BTh/BTl fp16 pair; MODE 2: BTh bf16.
template<int MODE, int DEPTH>
__global__ __launch_bounds__(256, 2)
void gemm_k(const unsigned short* __restrict__ Abf,
            const unsigned short* __restrict__ Agh,
            const unsigned short* __restrict__ Agl,
            const unsigned short* __restrict__ BTh,
            const unsigned short* __restrict__ BTl,
            const float* __restrict__ bias,
            const int* __restrict__ tokens,
            const float* __restrict__ emb,
            const float* __restrict__ sib,
            const float* __restrict__ Wg,
            float* __restrict__ gacc,
            const float* __restrict__ mArr,
            const float* __restrict__ cinv,
            const float* __restrict__ h0,
            float* __restrict__ nodes_next,
            unsigned short* __restrict__ nxh,
            unsigned short* __restrict__ nxl,
            float* __restrict__ f32out,
            unsigned short* __restrict__ pooled,
            float* __restrict__ out,
            int N)
{
    constexpr int K = 512;
    // fragment-contiguous LDS: slot s = kq*128 + m, 8 elems (16B) per slot
    __shared__ __align__(16) unsigned short Ah[BM*BK];
    __shared__ __align__(16) unsigned short Al[BM*BK];
    __shared__ __align__(16) unsigned short Bh[BK*BN];
    __shared__ __align__(16) unsigned short Bl[BK*BN];

    const int tid = threadIdx.x;
    const int w = tid >> 6, l = tid & 63;
    const int wr = w >> 1, wc = w & 1;

    int bx, by;
    if (MODE == 2){
        // XCD-bijective swizzle (8000 blocks % 8 == 0): each XCD gets a
        // contiguous 1000-tile chunk -> B working set ~4 MB, L2-resident
        int bid = blockIdx.x;
        int swz = (bid & 7) * 1000 + (bid >> 3);
        bx = swz & 31; by = swz >> 5;
    } else {
        bx = blockIdx.x; by = blockIdx.y;
    }
    const int row0 = bx * BM;
    const int n0   = by * BN;
    const int q = l >> 4, lm = l & 15;

    floatx4 acc[4][4]  = {};
    floatx4 accx[4][4] = {};

    // A-source row pointer (MODE 0: emb gather, split in VGPRs)
    const float* aptr = nullptr;
    const int am = tid & 127, kq0 = tid >> 7;
    if (MODE == 0) aptr = emb + (long)tokens[row0 + am] * K;

    long arow0 = 0, arow1 = 0;
    if (MODE != 0){
        arow0 = (long)(row0 + l) * K;
        arow1 = (long)(row0 + 64 + l) * K;
    }
    const long brow0 = (long)(n0 + l) * K;
    const long brow1 = (long)(n0 + 64 + l) * K;

    for (int k0 = 0; k0 < K; k0 += BK){
        __syncthreads();
        // stage B (hi): wave w covers kq=w, rows l and 64+l
        GLDS(BTh + brow0 + k0 + w*8, (char*)Bh + w*2048);
        GLDS(BTh + brow1 + k0 + w*8, (char*)Bh + w*2048 + 1024);
        if (MODE != 2){
            GLDS(BTl + brow0 + k0 + w*8, (char*)Bl + w*2048);
            GLDS(BTl + brow1 + k0 + w*8, (char*)Bl + w*2048 + 1024);
        }
        if (MODE == 1 || MODE == 3){
            // A pre-split limbs straight to LDS — no VALU split in the loop
            GLDS(Agh + arow0 + k0 + w*8, (char*)Ah + w*2048);
            GLDS(Agh + arow1 + k0 + w*8, (char*)Ah + w*2048 + 1024);
            GLDS(Agl + arow0 + k0 + w*8, (char*)Al + w*2048);
            GLDS(Agl + arow1 + k0 + w*8, (char*)Al + w*2048 + 1024);
        } else if (MODE == 2){
            GLDS(Abf + arow0 + k0 + w*8, (char*)Ah + w*2048);
            GLDS(Abf + arow1 + k0 + w*8, (char*)Ah + w*2048 + 1024);
        } else {
            // MODE 0: fp32 gather -> fp16 hi/lo limbs through VGPRs
#pragma unroll
            for (int t = 0; t < 2; t++){
                int kq = kq0 + 2*t;
                const float* src = aptr + k0 + kq*8;
                float xs[8];
                *(floatx4*)&xs[0] = *(const floatx4*)(src);
                *(floatx4*)&xs[4] = *(const floatx4*)(src + 4);
                unsigned short h8[8], l8[8];
#pragma unroll
                for (int e = 0; e < 8; e++) split_f16(xs[e], h8[e], l8[e]);
                int s = kq*128 + am;
                *(short8*)&Ah[s*8] = *(const short8*)h8;
                *(short8*)&Al[s*8] = *(const short8*)l8;
            }
        }
        __syncthreads();

        H8 bh[4], bl[4];
#pragma unroll
        for (int j = 0; j < 4; j++){
            bh[j].s = *(const short8*)&Bh[(q*128 + wc*64 + j*16 + lm)*8];
            if (MODE != 2)
                bl[j].s = *(const short8*)&Bl[(q*128 + wc*64 + j*16 + lm)*8];
        }
#pragma unroll
        for (int i = 0; i < 4; i++){
            H8 ah; ah.s = *(const short8*)&Ah[(q*128 + wr*64 + i*16 + lm)*8];
            if (MODE != 2){
                H8 al; al.s = *(const short8*)&Al[(q*128 + wr*64 + i*16 + lm)*8];
#pragma unroll
                for (int j = 0; j < 4; j++)
                    acc[i][j]  = __builtin_amdgcn_mfma_f32_16x16x32_f16(ah.h, bh[j].h, acc[i][j], 0, 0, 0);
#pragma unroll
                for (int j = 0; j < 4; j++)
                    accx[i][j] = __builtin_amdgcn_mfma_f32_16x16x32_f16(ah.h, bl[j].h, accx[i][j], 0, 0, 0);
#pragma unroll
                for (int j = 0; j < 4; j++)
                    accx[i][j] = __builtin_amdgcn_mfma_f32_16x16x32_f16(al.h, bh[j].h, accx[i][j], 0, 0, 0);
            } else {
#pragma unroll
                for (int j = 0; j < 4; j++)
                    acc[i][j] = __builtin_amdgcn_mfma_f32_16x16x32_bf16(ah.s, bh[j].s, acc[i][j], 0, 0, 0);
            }
        }
    }

    // epilogue: D[row=(l>>4)*4+r][col=l&15] per 16x16 frag
    // MODE<=1: also accumulate per-row gate dot (v * Wg[col]) -> gacc atomics
    float wgj[4];
    if (MODE <= 1){
#pragma unroll
        for (int j = 0; j < 4; j++)
            wgj[j] = Wg[(n0 + wc*64 + j*16 + lm) & 511];
    }
    const int halfc = n0 >> 9; // block-uniform (BN=128 divides 512)

#pragma unroll
    for (int i = 0; i < 4; i++){
        int rbase = row0 + wr*64 + i*16 + q*4;
        float gp[4] = {0.f, 0.f, 0.f, 0.f};
#pragma unroll
        for (int j = 0; j < 4; j++){
            int col = n0 + wc*64 + j*16 + lm;
            float badd = 0.f, bsum = 0.f;
            if (MODE == 0 || MODE == 2) badd = bias[col];
            if (MODE == 1) badd = bias[col] + SIBS * sib[halfc*512 + (col & 511)];
            if (MODE == 3)
                bsum = bias[col] + bias[512 + col] + SIBS * (sib[col] + sib[512 + col]);
#pragma unroll
            for (int r = 0; r < 4; r++){
                int row = rbase + r;
                float v = acc[i][j][r];
                if (MODE != 2) v += accx[i][j][r] * LS_INV;
                if (MODE == 0){
                    v += badd;
                    gp[r] += v * wgj[j];
                    long o = (long)row*512 + col;
                    f32out[o] = v;
                    unsigned short hh, ss; split_f16(v, hh, ss);
                    nxh[o] = hh; nxl[o] = ss;
                } else if (MODE == 1){
                    v += badd;
                    gp[r] += v * wgj[j];
                    long o = (long)(2*row + halfc)*512 + (col & 511);
                    nodes_next[o] = v;
                    if (DEPTH == 0){
                        unsigned short hh, ss; split_f16(v, hh, ss);
                        nxh[o] = hh; nxl[o] = ss;
                    }
                } else if (MODE == 3){
                    long o = (long)row*512 + col;
                    float outv = (h0[o] + v + mArr[row]*bsum) * cinv[row];
                    pooled[o] = f2bf(outv);
                } else {
                    out[(long)row*(long)N + col] = v + badd;
                }
            }
        }
        if (MODE <= 1){
#pragma unroll
            for (int r = 0; r < 4; r++){
                float s = gp[r];
                s += __shfl_xor(s, 1);
                s += __shfl_xor(s, 2);
                s += __shfl_xor(s, 4);
                s += __shfl_xor(s, 8);
                if (lm == 0){
                    int row = rbase + r;
                    int grow = (MODE == 0) ? row : (2*row + halfc);
                    atomicAdd(&gacc[grow], s);
                }
            }
        }
    }
}

// ---- masked sum: e-flags from gacc+cgate; S = sum of expanded nodes; m, 1/cnt ----
__global__ void msum_k(const float* __restrict__ nodes0,
                       const float* __restrict__ nodes1,
                       const float* __restrict__ nodes2,
                       const float* __restrict__ gacc,
                       const float* __restrict__ cgate,
                       unsigned short* __restrict__ Sh,
                       unsigned short* __restrict__ Sl,
                       float* __restrict__ mArr,
                       float* __restrict__ cinv)
{
    int n = blockIdx.x;
    const float* g0 = gacc;
    const float* g1 = gacc + 4096;
    const float* g2 = gacc + 12288;
    float c0 = cgate[0], c1 = cgate[1], c2 = cgate[2];
    bool b0  =  g0[n]       + c0 > 0.f;
    bool b10 = (g1[2*n]     + c1 > 0.f) && b0;
    bool b11 = (g1[2*n + 1] + c1 > 0.f) && b0;
    bool b20 = (g2[4*n]     + c2 > 0.f) && b10;
    bool b21 = (g2[4*n + 1] + c2 > 0.f) && b10;
    bool b22 = (g2[4*n + 2] + c2 > 0.f) && b11;
    bool b23 = (g2[4*n + 3] + c2 > 0.f) && b11;
    float a0  = (float)b0;
    float a10 = (float)b10, a11 = (float)b11;
    float a20 = (float)b20, a21 = (float)b21, a22 = (float)b22, a23 = (float)b23;
    if (threadIdx.x == 0){
        float m = a0 + a10 + a11 + a20 + a21 + a22 + a23;
        mArr[n] = m;
        cinv[n] = 1.f / (1.f + 2.f * m);
    }
    const float* p0 = nodes0 + (long)n * 512;
    const float* p1 = nodes1 + (long)(2*n) * 512;
    const float* p2 = nodes2 + (long)(4*n) * 512;
    for (int c = threadIdx.x; c < 512; c += 256){
        float s = a0 * p0[c]
                + a10 * p1[c]        + a11 * p1[512 + c]
                + a20 * p2[c]        + a21 * p2[512 + c]
                + a22 * p2[1024 + c] + a23 * p2[1536 + c];
        unsigned short hh, ss; split_f16(s, hh, ss);
        long o = (long)n * 512 + c;
        Sh[o] = hh; Sl[o] = ss;
    }
}

extern "C" void kernel_launch(void* const* d_in, const int* in_sizes, int n_in,
                              void* d_out, int out_size, void* d_ws, size_t ws_size,
                              hipStream_t stream)
{
    const int*   tokens = (const int*)d_in[0];
    const float* emb    = (const float*)d_in[1];
    const float* Wp     = (const float*)d_in[2];
    const float* bp     = (const float*)d_in[3];
    const float* Wc     = (const float*)d_in[4];
    const float* bc     = (const float*)d_in[5];
    const float* Wg     = (const float*)d_in[6];
    const float* bg     = (const float*)d_in[7];
    const float* dep    = (const float*)d_in[8];
    const float* sib    = (const float*)d_in[9];
    const float* Wout   = (const float*)d_in[10];
    const float* bout   = (const float*)d_in[11];

    if (ws_size < ((size_t)48 << 20)) return; // need ~42 MB scratch

    char* w = (char*)d_ws;
    auto alloc = [&](size_t bytes)->char*{
        char* p = w; w += (bytes + 255) & ~(size_t)255; return p;
    };
    unsigned short* WpT_h  = (unsigned short*)alloc((size_t)512*512*2);
    unsigned short* WpT_l  = (unsigned short*)alloc((size_t)512*512*2);
    unsigned short* WcT_h  = (unsigned short*)alloc((size_t)1024*512*2);
    unsigned short* WcT_l  = (unsigned short*)alloc((size_t)1024*512*2);
    unsigned short* Wc2T_h = (unsigned short*)alloc((size_t)512*512*2);
    unsigned short* Wc2T_l = (unsigned short*)alloc((size_t)512*512*2);
    unsigned short* WoutT  = (unsigned short*)alloc((size_t)32000*512*2);
    unsigned short* pooled = (unsigned short*)alloc((size_t)4096*512*2);
    float*          gacc   = (float*)alloc((size_t)28672*4); // 4096+8192+16384
    float*          cgate  = (float*)alloc(256);

    // All node/limb intermediates live inside d_out (500 MiB) — each is fully
    // consumed before the final GEMM overwrites the buffer with logits.
    char* ob = (char*)d_out;
    float*          nodes0 = (float*)(ob + ((size_t) 64 << 20)); //  8.4 MB
    unsigned short* n0h    = (unsigned short*)(ob + ((size_t) 80 << 20)); // 4.2
    unsigned short* n0l    = (unsigned short*)(ob + ((size_t) 88 << 20)); // 4.2
    float*          nodes1 = (float*)(ob + ((size_t) 96 << 20)); // 16.8 MB
    unsigned short* n1h    = (unsigned short*)(ob + ((size_t)128 << 20)); // 8.4
    unsigned short* n1l    = (unsigned short*)(ob + ((size_t)144 << 20)); // 8.4
    float*          nodes2 = (float*)(ob + ((size_t)160 << 20)); // 33.6 MB
    unsigned short* Sh     = (unsigned short*)(ob + ((size_t)200 << 20)); // 4.2
    unsigned short* Sl     = (unsigned short*)(ob + ((size_t)208 << 20)); // 4.2
    float*          mArr   = (float*)(ob + ((size_t)216 << 20)); // 16 KB
    float*          cinvA  = (float*)(ob + ((size_t)217 << 20)); // 16 KB
    float*          out    = (float*)d_out;

    // one fused prep dispatch: all weight transposes + gacc zero + gate consts
    prep_all<<<17033, 256, 0, stream>>>(Wp, Wc, Wout, Wg, bg, dep,
        WpT_h, WpT_l, WcT_h, WcT_l, Wc2T_h, Wc2T_l, WoutT, gacc, cgate);

    // h0 = emb[tok] @ Wp + bp -> nodes0 fp32 + limb pair; gate dots -> gacc[0:4096)
    gemm_k<0,0><<<dim3(32, 4), 256, 0, stream>>>(nullptr, nullptr, nullptr,
        WpT_h, WpT_l, bp, tokens, emb, nullptr, Wg, gacc,
        nullptr, nullptr, nullptr, nullptr, n0h, n0l, nodes0, nullptr, nullptr, 512);

    // depth-0 children -> nodes1 fp32 + limbs; gate dots -> gacc[4096:12288)
    gemm_k<1,0><<<dim3(32, 8), 256, 0, stream>>>(nullptr, n0h, n0l,
        WcT_h, WcT_l, bc, nullptr, nullptr, sib, Wg, gacc + 4096,
        nullptr, nullptr, nullptr, nodes1, n1h, n1l, nullptr, nullptr, nullptr, 1024);

    // depth-1 children -> nodes2 fp32; gate dots -> gacc[12288:28672)
    gemm_k<1,1><<<dim3(64, 8), 256, 0, stream>>>(nullptr, n1h, n1l,
        WcT_h, WcT_l, bc, nullptr, nullptr, sib, Wg, gacc + 12288,
        nullptr, nullptr, nullptr, nodes2, nullptr, nullptr, nullptr, nullptr, nullptr, 1024);

    // e-flags from gacc; S = masked sum of expanded nodes; m, 1/cnt per token
    msum_k<<<4096, 256, 0, stream>>>(nodes0, nodes1, nodes2, gacc, cgate,
        Sh, Sl, mArr, cinvA);

    // pooled = bf16((h0 + S@Wc2 + m*const) / cnt)
    gemm_k<3,0><<<dim3(32, 4), 256, 0, stream>>>(nullptr, Sh, Sl,
        Wc2T_h, Wc2T_l, bc, nullptr, nullptr, sib, nullptr, nullptr,
        mArr, cinvA, nodes0, nullptr, nullptr, nullptr, nullptr, pooled, nullptr, 512);

    // logits = pooled @ Wout + bout (bf16 MFMA, fp32 out), XCD-swizzled 1D grid
    gemm_k<2,0><<<dim3(8000), 256, 0, stream>>>(pooled, nullptr, nullptr,
        WoutT, nullptr, bout, nullptr, nullptr, nullptr, nullptr, nullptr,
        nullptr, nullptr, nullptr, nullptr, nullptr, nullptr, nullptr, nullptr, out, 32000);
}

// Round 4
// 959.070 us; speedup vs baseline: 1.0584x; 1.0461x over previous
//
#include <hip/hip_runtime.h>
#include <cstdint>

#define BM 128
#define BN 128
#define BK 32

typedef __attribute__((ext_vector_type(8))) short short8;
typedef _Float16 half8 __attribute__((ext_vector_type(8)));
typedef __attribute__((ext_vector_type(4))) float floatx4;

union H8 { short8 s; half8 h; };

static constexpr float SIBS   = 0.044194173824159216f; // 1/sqrt(512)
static constexpr float LS_INV = 1.0f / 2048.0f;

__device__ __forceinline__ unsigned short f2bf(float x){
    union { float f; unsigned u32; } v; v.f = x;
    unsigned r = ((v.u32 >> 16) & 1u) + 0x7fffu;
    return (unsigned short)((v.u32 + r) >> 16);
}
__device__ __forceinline__ void split_f16(float x, unsigned short& h, unsigned short& s){
    _Float16 hh = (_Float16)x;
    _Float16 ss = (_Float16)((x - (float)hh) * 2048.0f);
    union { _Float16 f; unsigned short u; } a, b;
    a.f = hh; b.f = ss;
    h = a.u; s = b.u;
}

#define GLDS(g, l) __builtin_amdgcn_global_load_lds( \
    (const __attribute__((address_space(1))) void*)(g), \
    (__attribute__((address_space(3))) void*)(l), 16, 0, 0)

// ---------------- fused prep (one dispatch) ----------------
// blocks [0,256)        : WpT hi/lo split-transpose (512x512)
// blocks [256,768)      : WcT hi/lo split-transpose (512x1024)
// blocks [768,1024)     : Wc2T = (WcL+WcR) hi/lo split-transpose (512x512)
// blocks [1024,17024)   : WoutT bf16 transpose (512x32000)
// blocks [17024,17032)  : zero gacc (28672 floats)
// block  17032          : cgate[d] = 0.01*dep[d].Wg + bg, d=0..2
__global__ void prep_all(const float* __restrict__ Wp, const float* __restrict__ Wc,
                         const float* __restrict__ Wout, const float* __restrict__ Wg,
                         const float* __restrict__ bg, const float* __restrict__ dep,
                         unsigned short* __restrict__ WpT_h, unsigned short* __restrict__ WpT_l,
                         unsigned short* __restrict__ WcT_h, unsigned short* __restrict__ WcT_l,
                         unsigned short* __restrict__ Wc2T_h, unsigned short* __restrict__ Wc2T_l,
                         unsigned short* __restrict__ WoutT,
                         float* __restrict__ gacc, float* __restrict__ cgate)
{
    int bid = blockIdx.x;
    if (bid >= 17024){
        if (bid < 17032){
            int base = (bid - 17024)*3584 + threadIdx.x;
#pragma unroll
            for (int k = 0; k < 14; k++) gacc[base + k*256] = 0.f;
        } else {
            int wv = threadIdx.x >> 6, l = threadIdx.x & 63;
            if (wv < 3){
                float s = 0.f;
#pragma unroll
                for (int t = 0; t < 8; t++){
                    int h = t*64 + l;
                    s += dep[wv*512 + h] * Wg[h];
                }
#pragma unroll
                for (int off = 32; off > 0; off >>= 1) s += __shfl_down(s, off);
                if (l == 0) cgate[wv] = 0.01f*s + bg[0];
            }
        }
        return;
    }
    __shared__ float t[32][33];
    const float* src = nullptr;
    unsigned short *dh = nullptr, *dl = nullptr;
    int C = 512, bx, by; bool sum2 = false;
    if (bid < 256){ src=Wp; dh=WpT_h; dl=WpT_l; C=512; bx=bid&15; by=bid>>4; }
    else if (bid < 768){ int rel=bid-256; src=Wc; dh=WcT_h; dl=WcT_l; C=1024; bx=rel&31; by=rel>>5; }
    else if (bid < 1024){ int rel=bid-768; src=Wc; dh=Wc2T_h; dl=Wc2T_l; C=512; sum2=true; bx=rel&15; by=rel>>4; }
    else { int rel=bid-1024; src=Wout; dh=WoutT; dl=nullptr; C=32000; bx=rel%1000; by=rel/1000; }
    int c0 = bx*32, r0 = by*32;
    int tx = threadIdx.x & 31, ty = threadIdx.x >> 5;
#pragma unroll
    for (int k = 0; k < 4; k++){
        int r = ty + k*8;
        float x;
        if (sum2) x = Wc[(size_t)(r0+r)*1024 + c0+tx] + Wc[(size_t)(r0+r)*1024 + 512 + c0+tx];
        else      x = src[(size_t)(r0+r)*C + c0+tx];
        t[r][tx] = x;
    }
    __syncthreads();
#pragma unroll
    for (int k = 0; k < 4; k++){
        int r = ty + k*8;
        float x = t[tx][r]; // = src[r0+tx][c0+r]
        size_t o = (size_t)(c0+r)*512 + r0+tx;
        if (dl){
            unsigned short h, s; split_f16(x, h, s);
            dh[o] = h; dl[o] = s;
        } else {
            dh[o] = f2bf(x);
        }
    }
}

// ---------------- unified GEMM (small shapes: MODES 0,1,3) ----------------
// MODE 0: h0   — A = gathered emb rows (fp32 -> fp16 2-limb in-kernel),
//                writes nodes0 fp32 + limb arrays; gate-dot atomics -> gacc
// MODE 1: tree — A = pre-split limb arrays via GLDS, +bc+sib,
//                writes nodes_next fp32 (+ limbs when DEPTH==0); gate-dot -> gacc
// MODE 3: agg  — A = S limbs, B = Wc2T limbs; epilogue fuses
//                pooled = bf16((h0 + S@Wc2 + m*constv) / cnt)
// B pre-transposed [N][K], K=512; BTh/BTl fp16 pair.
template<int MODE, int DEPTH>
__global__ __launch_bounds__(256, 2)
void gemm_k(const unsigned short* __restrict__ Agh,
            const unsigned short* __restrict__ Agl,
            const unsigned short* __restrict__ BTh,
            const unsigned short* __restrict__ BTl,
            const float* __restrict__ bias,
            const int* __restrict__ tokens,
            const float* __restrict__ emb,
            const float* __restrict__ sib,
            const float* __restrict__ Wg,
            float* __restrict__ gacc,
            const float* __restrict__ mArr,
            const float* __restrict__ cinv,
            const float* __restrict__ h0,
            float* __restrict__ nodes_next,
            unsigned short* __restrict__ nxh,
            unsigned short* __restrict__ nxl,
            float* __restrict__ f32out,
            unsigned short* __restrict__ pooled,
            int N)
{
    constexpr int K = 512;
    // fragment-contiguous LDS: slot s = kq*128 + m, 8 elems (16B) per slot
    __shared__ __align__(16) unsigned short Ah[BM*BK];
    __shared__ __align__(16) unsigned short Al[BM*BK];
    __shared__ __align__(16) unsigned short Bh[BK*BN];
    __shared__ __align__(16) unsigned short Bl[BK*BN];

    const int tid = threadIdx.x;
    const int w = tid >> 6, l = tid & 63;
    const int wr = w >> 1, wc = w & 1;
    const int row0 = blockIdx.x * BM;
    const int n0   = blockIdx.y * BN;
    const int q = l >> 4, lm = l & 15;

    floatx4 acc[4][4]  = {};
    floatx4 accx[4][4] = {};

    // A-source row pointer (MODE 0: emb gather, split in VGPRs)
    const float* aptr = nullptr;
    const int am = tid & 127, kq0 = tid >> 7;
    if (MODE == 0) aptr = emb + (long)tokens[row0 + am] * K;

    long arow0 = 0, arow1 = 0;
    if (MODE != 0){
        arow0 = (long)(row0 + l) * K;
        arow1 = (long)(row0 + 64 + l) * K;
    }
    const long brow0 = (long)(n0 + l) * K;
    const long brow1 = (long)(n0 + 64 + l) * K;

    for (int k0 = 0; k0 < K; k0 += BK){
        __syncthreads();
        // stage B: wave w covers kq=w, rows l and 64+l
        GLDS(BTh + brow0 + k0 + w*8, (char*)Bh + w*2048);
        GLDS(BTh + brow1 + k0 + w*8, (char*)Bh + w*2048 + 1024);
        GLDS(BTl + brow0 + k0 + w*8, (char*)Bl + w*2048);
        GLDS(BTl + brow1 + k0 + w*8, (char*)Bl + w*2048 + 1024);
        if (MODE == 1 || MODE == 3){
            // A pre-split limbs straight to LDS — no VALU split in the loop
            GLDS(Agh + arow0 + k0 + w*8, (char*)Ah + w*2048);
            GLDS(Agh + arow1 + k0 + w*8, (char*)Ah + w*2048 + 1024);
            GLDS(Agl + arow0 + k0 + w*8, (char*)Al + w*2048);
            GLDS(Agl + arow1 + k0 + w*8, (char*)Al + w*2048 + 1024);
        } else {
            // MODE 0: fp32 gather -> fp16 hi/lo limbs through VGPRs
#pragma unroll
            for (int t = 0; t < 2; t++){
                int kq = kq0 + 2*t;
                const float* src = aptr + k0 + kq*8;
                float xs[8];
                *(floatx4*)&xs[0] = *(const floatx4*)(src);
                *(floatx4*)&xs[4] = *(const floatx4*)(src + 4);
                unsigned short h8[8], l8[8];
#pragma unroll
                for (int e = 0; e < 8; e++) split_f16(xs[e], h8[e], l8[e]);
                int s = kq*128 + am;
                *(short8*)&Ah[s*8] = *(const short8*)h8;
                *(short8*)&Al[s*8] = *(const short8*)l8;
            }
        }
        __syncthreads();

        H8 bh[4], bl[4];
#pragma unroll
        for (int j = 0; j < 4; j++){
            bh[j].s = *(const short8*)&Bh[(q*128 + wc*64 + j*16 + lm)*8];
            bl[j].s = *(const short8*)&Bl[(q*128 + wc*64 + j*16 + lm)*8];
        }
#pragma unroll
        for (int i = 0; i < 4; i++){
            H8 ah; ah.s = *(const short8*)&Ah[(q*128 + wr*64 + i*16 + lm)*8];
            H8 al; al.s = *(const short8*)&Al[(q*128 + wr*64 + i*16 + lm)*8];
#pragma unroll
            for (int j = 0; j < 4; j++)
                acc[i][j]  = __builtin_amdgcn_mfma_f32_16x16x32_f16(ah.h, bh[j].h, acc[i][j], 0, 0, 0);
#pragma unroll
            for (int j = 0; j < 4; j++)
                accx[i][j] = __builtin_amdgcn_mfma_f32_16x16x32_f16(ah.h, bl[j].h, accx[i][j], 0, 0, 0);
#pragma unroll
            for (int j = 0; j < 4; j++)
                accx[i][j] = __builtin_amdgcn_mfma_f32_16x16x32_f16(al.h, bh[j].h, accx[i][j], 0, 0, 0);
        }
    }

    // epilogue: D[row=(l>>4)*4+r][col=l&15] per 16x16 frag
    // MODE<=1: also accumulate per-row gate dot (v * Wg[col]) -> gacc atomics
    float wgj[4];
    if (MODE <= 1){
#pragma unroll
        for (int j = 0; j < 4; j++)
            wgj[j] = Wg[(n0 + wc*64 + j*16 + lm) & 511];
    }
    const int halfc = n0 >> 9; // block-uniform (BN=128 divides 512)

#pragma unroll
    for (int i = 0; i < 4; i++){
        int rbase = row0 + wr*64 + i*16 + q*4;
        float gp[4] = {0.f, 0.f, 0.f, 0.f};
#pragma unroll
        for (int j = 0; j < 4; j++){
            int col = n0 + wc*64 + j*16 + lm;
            float badd = 0.f, bsum = 0.f;
            if (MODE == 0) badd = bias[col];
            if (MODE == 1) badd = bias[col] + SIBS * sib[halfc*512 + (col & 511)];
            if (MODE == 3)
                bsum = bias[col] + bias[512 + col] + SIBS * (sib[col] + sib[512 + col]);
#pragma unroll
            for (int r = 0; r < 4; r++){
                int row = rbase + r;
                float v = acc[i][j][r] + accx[i][j][r] * LS_INV;
                if (MODE == 0){
                    v += badd;
                    gp[r] += v * wgj[j];
                    long o = (long)row*512 + col;
                    f32out[o] = v;
                    unsigned short hh, ss; split_f16(v, hh, ss);
                    nxh[o] = hh; nxl[o] = ss;
                } else if (MODE == 1){
                    v += badd;
                    gp[r] += v * wgj[j];
                    long o = (long)(2*row + halfc)*512 + (col & 511);
                    nodes_next[o] = v;
                    if (DEPTH == 0){
                        unsigned short hh, ss; split_f16(v, hh, ss);
                        nxh[o] = hh; nxl[o] = ss;
                    }
                } else {
                    long o = (long)row*512 + col;
                    float outv = (h0[o] + v + mArr[row]*bsum) * cinv[row];
                    pooled[o] = f2bf(outv);
                }
            }
        }
        if (MODE <= 1){
#pragma unroll
            for (int r = 0; r < 4; r++){
                float s = gp[r];
                s += __shfl_xor(s, 1);
                s += __shfl_xor(s, 2);
                s += __shfl_xor(s, 4);
                s += __shfl_xor(s, 8);
                if (lm == 0){
                    int row = rbase + r;
                    int grow = (MODE == 0) ? row : (2*row + halfc);
                    atomicAdd(&gacc[grow], s);
                }
            }
        }
    }
}

// ---------------- final GEMM: out = pooled(bf16) @ WoutT^T + bout ----------------
// BM=256 x BN=128 x BK=64, 512 threads (8 waves, 4M x 2N), K=512 -> 8 K-tiles.
// 3-buffer LDS rotation (3 x 48 KB = 144 KB), counted vmcnt (12/6/0) — loads for
// K-tile u+2 stay in flight across barriers while computing K-tile u (T3/T4).
// LDS bank fix: kq_phys = kq_log ^ (row&7) involution, applied on the GLOBAL
// source at staging (linear GLDS dest) and on the ds_read address (rule 21).
__global__ __launch_bounds__(512, 2)
void gemm_out(const unsigned short* __restrict__ pooled, // [4096][512] bf16
              const unsigned short* __restrict__ BT,     // [32000][512] bf16
              const float* __restrict__ bout,
              float* __restrict__ out)
{
    constexpr int K = 512;
    constexpr int NT = 8;                 // K-tiles of 64
    constexpr int BUFS = 24576;           // shorts per buffer: A 16384 + B 8192
    __shared__ __align__(16) unsigned short lds[3 * BUFS]; // 144 KB

    const int tid = threadIdx.x;
    const int w = tid >> 6, l = tid & 63;
    const int wm = w >> 1, wn = w & 1;    // 4 x 2 wave grid, per-wave 64x64 out
    const int q = l >> 4, lm = l & 15;

    // XCD-bijective swizzle: 4000 blocks, chunk 500/XCD; within chunk n-major
    // (~31 B-panels + all A per XCD -> L2/L3-resident working set)
    const int bid = blockIdx.x;
    const int swz = (bid & 7) * 500 + (bid >> 3);
    const int m0 = (swz & 15) * 256;
    const int n0 = (swz >> 4) * 128;

    // staging geometry: issue t covers rows [t*8, t*8+8), lane l -> row t*8+(l>>3),
    // phys kq = l&7 holds logical kq = (l&7)^((l>>3)&7)  (involution per row)
    const int lr = l >> 3;
    const int kq = (l & 7) ^ (lr & 7);
    long asrc[4]; long bsrc[2];
#pragma unroll
    for (int a = 0; a < 4; a++){
        int t = w + 8*a;                  // A: 32 issues, wave w takes w+8a
        asrc[a] = (long)(m0 + t*8 + lr) * K + kq*8;
    }
#pragma unroll
    for (int b = 0; b < 2; b++){
        int t = w + 8*b;                  // B: 16 issues, wave w takes w+8b
        bsrc[b] = (long)(n0 + t*8 + lr) * K + kq*8;
    }

    auto ostage = [&](int u){             // u compile-time (unrolled callers)
        unsigned short* base = lds + (u % 3) * BUFS;
        const int k0 = u * 64;
#pragma unroll
        for (int a = 0; a < 4; a++)
            GLDS(pooled + asrc[a] + k0, (char*)base + (w + 8*a)*1024);
#pragma unroll
        for (int b = 0; b < 2; b++)
            GLDS(BT + bsrc[b] + k0, (char*)base + 32768 + (w + 8*b)*1024);
    };

    floatx4 acc[4][4] = {};

    ostage(0); ostage(1);                 // prologue: 12 loads in flight

#pragma unroll
    for (int u = 0; u < NT; u++){
        if (u < NT-2) ostage(u+2);        // 6 more loads -> 18 outstanding
        // wait until stage(u) fully landed (per-wave), then barrier -> all waves
        if (u < NT-2)       asm volatile("s_waitcnt vmcnt(12)" ::: "memory");
        else if (u == NT-2) asm volatile("s_waitcnt vmcnt(6)"  ::: "memory");
        else                asm volatile("s_waitcnt vmcnt(0)"  ::: "memory");
        __builtin_amdgcn_s_barrier();
        __builtin_amdgcn_sched_barrier(0);

        const unsigned short* base  = lds + (u % 3) * BUFS;
        const unsigned short* bbase = base + 16384;
#pragma unroll
        for (int s = 0; s < 2; s++){
            H8 aF[4], bF[4];
#pragma unroll
            for (int i = 0; i < 4; i++){
                int row = wm*64 + i*16 + lm;
                aF[i].s = *(const short8*)&base[(row*8 + ((s*4+q) ^ (lm&7)))*8];
            }
#pragma unroll
            for (int j = 0; j < 4; j++){
                int col = wn*64 + j*16 + lm;
                bF[j].s = *(const short8*)&bbase[(col*8 + ((s*4+q) ^ (lm&7)))*8];
            }
            __builtin_amdgcn_s_setprio(1);
#pragma unroll
            for (int i = 0; i < 4; i++)
#pragma unroll
                for (int j = 0; j < 4; j++)
                    acc[i][j] = __builtin_amdgcn_mfma_f32_16x16x32_bf16(aF[i].s, bF[j].s, acc[i][j], 0, 0, 0);
            __builtin_amdgcn_s_setprio(0);
        }
        // all reads of buf[u] done before next iter's stage targets it
        __builtin_amdgcn_s_barrier();
        __builtin_amdgcn_sched_barrier(0);
    }

    // epilogue: D[row = i*16 + q*4 + r][col = j*16 + lm] per fragment
#pragma unroll
    for (int i = 0; i < 4; i++){
        int rbase = m0 + wm*64 + i*16 + q*4;
#pragma unroll
        for (int j = 0; j < 4; j++){
            int col = n0 + wn*64 + j*16 + lm;
            float badd = bout[col];
#pragma unroll
            for (int r = 0; r < 4; r++)
                out[(long)(rbase + r)*32000L + col] = acc[i][j][r] + badd;
        }
    }
}

// ---- masked sum: e-flags from gacc+cgate; S = sum of expanded nodes; m, 1/cnt ----
__global__ void msum_k(const float* __restrict__ nodes0,
                       const float* __restrict__ nodes1,
                       const float* __restrict__ nodes2,
                       const float* __restrict__ gacc,
                       const float* __restrict__ cgate,
                       unsigned short* __restrict__ Sh,
                       unsigned short* __restrict__ Sl,
                       float* __restrict__ mArr,
                       float* __restrict__ cinv)
{
    int n = blockIdx.x;
    const float* g0 = gacc;
    const float* g1 = gacc + 4096;
    const float* g2 = gacc + 12288;
    float c0 = cgate[0], c1 = cgate[1], c2 = cgate[2];
    bool b0  =  g0[n]       + c0 > 0.f;
    bool b10 = (g1[2*n]     + c1 > 0.f) && b0;
    bool b11 = (g1[2*n + 1] + c1 > 0.f) && b0;
    bool b20 = (g2[4*n]     + c2 > 0.f) && b10;
    bool b21 = (g2[4*n + 1] + c2 > 0.f) && b10;
    bool b22 = (g2[4*n + 2] + c2 > 0.f) && b11;
    bool b23 = (g2[4*n + 3] + c2 > 0.f) && b11;
    float a0  = (float)b0;
    float a10 = (float)b10, a11 = (float)b11;
    float a20 = (float)b20, a21 = (float)b21, a22 = (float)b22, a23 = (float)b23;
    if (threadIdx.x == 0){
        float m = a0 + a10 + a11 + a20 + a21 + a22 + a23;
        mArr[n] = m;
        cinv[n] = 1.f / (1.f + 2.f * m);
    }
    const float* p0 = nodes0 + (long)n * 512;
    const float* p1 = nodes1 + (long)(2*n) * 512;
    const float* p2 = nodes2 + (long)(4*n) * 512;
    for (int c = threadIdx.x; c < 512; c += 256){
        float s = a0 * p0[c]
                + a10 * p1[c]        + a11 * p1[512 + c]
                + a20 * p2[c]        + a21 * p2[512 + c]
                + a22 * p2[1024 + c] + a23 * p2[1536 + c];
        unsigned short hh, ss; split_f16(s, hh, ss);
        long o = (long)n * 512 + c;
        Sh[o] = hh; Sl[o] = ss;
    }
}

extern "C" void kernel_launch(void* const* d_in, const int* in_sizes, int n_in,
                              void* d_out, int out_size, void* d_ws, size_t ws_size,
                              hipStream_t stream)
{
    const int*   tokens = (const int*)d_in[0];
    const float* emb    = (const float*)d_in[1];
    const float* Wp     = (const float*)d_in[2];
    const float* bp     = (const float*)d_in[3];
    const float* Wc     = (const float*)d_in[4];
    const float* bc     = (const float*)d_in[5];
    const float* Wg     = (const float*)d_in[6];
    const float* bg     = (const float*)d_in[7];
    const float* dep    = (const float*)d_in[8];
    const float* sib    = (const float*)d_in[9];
    const float* Wout   = (const float*)d_in[10];
    const float* bout   = (const float*)d_in[11];

    if (ws_size < ((size_t)48 << 20)) return; // need ~42 MB scratch

    char* w = (char*)d_ws;
    auto alloc = [&](size_t bytes)->char*{
        char* p = w; w += (bytes + 255) & ~(size_t)255; return p;
    };
    unsigned short* WpT_h  = (unsigned short*)alloc((size_t)512*512*2);
    unsigned short* WpT_l  = (unsigned short*)alloc((size_t)512*512*2);
    unsigned short* WcT_h  = (unsigned short*)alloc((size_t)1024*512*2);
    unsigned short* WcT_l  = (unsigned short*)alloc((size_t)1024*512*2);
    unsigned short* Wc2T_h = (unsigned short*)alloc((size_t)512*512*2);
    unsigned short* Wc2T_l = (unsigned short*)alloc((size_t)512*512*2);
    unsigned short* WoutT  = (unsigned short*)alloc((size_t)32000*512*2);
    unsigned short* pooled = (unsigned short*)alloc((size_t)4096*512*2);
    float*          gacc   = (float*)alloc((size_t)28672*4); // 4096+8192+16384
    float*          cgate  = (float*)alloc(256);

    // All node/limb intermediates live inside d_out (500 MiB) — each is fully
    // consumed before the final GEMM overwrites the buffer with logits.
    char* ob = (char*)d_out;
    float*          nodes0 = (float*)(ob + ((size_t) 64 << 20)); //  8.4 MB
    unsigned short* n0h    = (unsigned short*)(ob + ((size_t) 80 << 20)); // 4.2
    unsigned short* n0l    = (unsigned short*)(ob + ((size_t) 88 << 20)); // 4.2
    float*          nodes1 = (float*)(ob + ((size_t) 96 << 20)); // 16.8 MB
    unsigned short* n1h    = (unsigned short*)(ob + ((size_t)128 << 20)); // 8.4
    unsigned short* n1l    = (unsigned short*)(ob + ((size_t)144 << 20)); // 8.4
    float*          nodes2 = (float*)(ob + ((size_t)160 << 20)); // 33.6 MB
    unsigned short* Sh     = (unsigned short*)(ob + ((size_t)200 << 20)); // 4.2
    unsigned short* Sl     = (unsigned short*)(ob + ((size_t)208 << 20)); // 4.2
    float*          mArr   = (float*)(ob + ((size_t)216 << 20)); // 16 KB
    float*          cinvA  = (float*)(ob + ((size_t)217 << 20)); // 16 KB
    float*          out    = (float*)d_out;

    // one fused prep dispatch: all weight transposes + gacc zero + gate consts
    prep_all<<<17033, 256, 0, stream>>>(Wp, Wc, Wout, Wg, bg, dep,
        WpT_h, WpT_l, WcT_h, WcT_l, Wc2T_h, Wc2T_l, WoutT, gacc, cgate);

    // h0 = emb[tok] @ Wp + bp -> nodes0 fp32 + limb pair; gate dots -> gacc[0:4096)
    gemm_k<0,0><<<dim3(32, 4), 256, 0, stream>>>(nullptr, nullptr,
        WpT_h, WpT_l, bp, tokens, emb, nullptr, Wg, gacc,
        nullptr, nullptr, nullptr, nullptr, n0h, n0l, nodes0, nullptr, 512);

    // depth-0 children -> nodes1 fp32 + limbs; gate dots -> gacc[4096:12288)
    gemm_k<1,0><<<dim3(32, 8), 256, 0, stream>>>(n0h, n0l,
        WcT_h, WcT_l, bc, nullptr, nullptr, sib, Wg, gacc + 4096,
        nullptr, nullptr, nullptr, nodes1, n1h, n1l, nullptr, nullptr, 1024);

    // depth-1 children -> nodes2 fp32; gate dots -> gacc[12288:28672)
    gemm_k<1,1><<<dim3(64, 8), 256, 0, stream>>>(n1h, n1l,
        WcT_h, WcT_l, bc, nullptr, nullptr, sib, Wg, gacc + 12288,
        nullptr, nullptr, nullptr, nodes2, nullptr, nullptr, nullptr, nullptr, 1024);

    // e-flags from gacc; S = masked sum of expanded nodes; m, 1/cnt per token
    msum_k<<<4096, 256, 0, stream>>>(nodes0, nodes1, nodes2, gacc, cgate,
        Sh, Sl, mArr, cinvA);

    // pooled = bf16((h0 + S@Wc2 + m*const) / cnt)
    gemm_k<3,0><<<dim3(32, 4), 256, 0, stream>>>(Sh, Sl,
        Wc2T_h, Wc2T_l, bc, nullptr, nullptr, sib, nullptr, nullptr,
        mArr, cinvA, nodes0, nullptr, nullptr, nullptr, nullptr, pooled, 512);

    // logits = pooled @ Wout + bout — 256x128x64 pipelined kernel, counted vmcnt
    gemm_out<<<4000, 512, 0, stream>>>(pooled, WoutT, bout, out);
}